// Round 5
// baseline (161.063 us; speedup 1.0000x reference)
//
#include <hip/hip_runtime.h>
#include <math.h>
#include <stdint.h>

#define B_    8
#define N_    3136
#define DIM_  147
#define KP_   160
#define TOK_  (B_*N_)      // 25088
#define QKV3_ 192
#define NSPLIT 4

typedef __attribute__((ext_vector_type(4)))  float f32x4;
typedef __attribute__((ext_vector_type(16))) float f32x16;
typedef __attribute__((ext_vector_type(4)))  unsigned int u32x4;
typedef __attribute__((ext_vector_type(2)))  unsigned int u32x2;
typedef __attribute__((ext_vector_type(8)))  short short8;
typedef float f32x4u __attribute__((ext_vector_type(4), aligned(4)));  // 4B-aligned vector load
typedef union { short8 s; u32x4 u; } pk8;

static __device__ __forceinline__ unsigned short f2b(float f){
  unsigned int u = __float_as_uint(f);
  u += 0x7fffu + ((u>>16)&1u);          // RNE
  return (unsigned short)(u>>16);
}
static __device__ __forceinline__ unsigned int pk2(float a, float b){   // RNE pack
  return ((unsigned int)f2b(b)<<16) | (unsigned int)f2b(a);
}
static __device__ __forceinline__ unsigned int pk2t(float a, float b){  // trunc pack (P only)
  return (__float_as_uint(b) & 0xffff0000u) | (__float_as_uint(a)>>16);
}
static __device__ __forceinline__ float b2f(unsigned short s){
  return __uint_as_float(((unsigned int)s)<<16);
}

// ---------------------------------------------------------------- K1: fused LN1 + QKV GEMM
__global__ __launch_bounds__(256) void k_qkv(const float* __restrict__ x,
                                             const float* __restrict__ w1,
                                             const float* __restrict__ b1,
                                             const float* __restrict__ qkvw,
                                             const float* __restrict__ scale,
                                             unsigned short* __restrict__ qb,
                                             unsigned short* __restrict__ kb,
                                             unsigned short* __restrict__ vtb,
                                             unsigned short* __restrict__ vfb){
  __shared__ alignas(16) unsigned short Wb[192*168];  // 64512 B; aliased by A_ and VT
  unsigned short* A_ = Wb;
  unsigned short* VT = Wb;
  int tid = threadIdx.x;
  int w = tid>>6, lane = tid&63, quad = lane>>4, l16 = lane&15;
  int t0 = blockIdx.x*64;
  float sc2 = scale[0] * 1.44269504089f;

  #pragma unroll
  for(int half=0; half<2; half++){
    int g = half*32 + (tid>>3), e = tid&7;
    const float* xr = x + (size_t)(t0+g)*147;
    f32x4u xv[5];
    float s = 0.f, sq = 0.f;
    #pragma unroll
    for(int j=0;j<5;j++){
      int k = e + 8*j;                      // chunk index, cols 4k..4k+3
      int keff = (k > 36) ? 36 : k;         // clamp addr (masked lanes reuse chunk 36)
      f32x4u v = *(const f32x4u*)(xr + 4*keff);
      if(j == 4){                           // k in [32,39]: mask tail
        v[0] = (k<=36) ? v[0] : 0.f;
        v[1] = (k<=36) ? v[1] : 0.f;
        v[2] = (k<=36) ? v[2] : 0.f;
        v[3] = (k< 36) ? v[3] : 0.f;        // col 147 invalid at k==36
      }
      xv[j] = v;
      s  += (v[0]+v[1]) + (v[2]+v[3]);
      sq += (v[0]*v[0]+v[1]*v[1]) + (v[2]*v[2]+v[3]*v[3]);
    }
    s  += __shfl_xor(s,1,64);  s  += __shfl_xor(s,2,64);  s  += __shfl_xor(s,4,64);
    sq += __shfl_xor(sq,1,64); sq += __shfl_xor(sq,2,64); sq += __shfl_xor(sq,4,64);
    float mean = s*(1.f/147.f);
    float var  = sq*(1.f/147.f) - mean*mean;
    float rstd = rsqrtf(var + 1e-5f);
    #pragma unroll
    for(int j=0;j<5;j++){
      int k = e + 8*j;
      unsigned int lo = 0u, hi = 0u;
      if(k <= 36){
        int c0 = 4*k;
        int c3 = (k==36) ? 146 : c0+3;      // don't read w1/b1 past 146
        float y0 = (xv[j][0]-mean)*rstd*w1[c0]   + b1[c0];
        float y1 = (xv[j][1]-mean)*rstd*w1[c0+1] + b1[c0+1];
        float y2 = (xv[j][2]-mean)*rstd*w1[c0+2] + b1[c0+2];
        float y3 = (xv[j][3]-mean)*rstd*w1[c3]   + b1[c3];
        if(k == 36) y3 = 0.f;               // col 147 -> 0 (K padding)
        lo = pk2(y0,y1); hi = pk2(y2,y3);
      }
      *(u32x2*)(A_ + g*168 + 4*k) = (u32x2){lo,hi};   // k>36 lanes zero cols 148..159
    }
  }
  __syncthreads();
  short8 Af[5];
  #pragma unroll
  for(int kk=0;kk<5;kk++)
    Af[kk] = *(const short8*)(A_ + (w*16+l16)*168 + kk*32 + quad*8);
  __syncthreads();
  {
    // stage qkv weights: convert f32 -> bf16 inline
    unsigned int* dst = (unsigned int*)Wb;
    #pragma unroll
    for(int rep=0; rep<15; rep++){
      int idx = rep*256 + tid;
      int row = idx/20, c = idx - row*20;
      u32x4 o = (u32x4){0u,0u,0u,0u};
      if(c < 19){
        const float* sp = qkvw + row*147 + c*8;
        f32x4u a = *(const f32x4u*)sp;
        o[0] = pk2(a[0],a[1]);
        if(c < 18){
          f32x4u bv = *(const f32x4u*)(sp+4);
          o[1] = pk2(a[2],a[3]);
          o[2] = pk2(bv[0],bv[1]);
          o[3] = pk2(bv[2],bv[3]);
        } else {
          o[1] = pk2(a[2],0.f);             // col 147 of row = next row's elem -> masked
        }
      }
      *(u32x4*)(dst + row*84 + c*4) = o;
    }
  }
  __syncthreads();
  f32x4 acc[12];
  #pragma unroll
  for(int i=0;i<12;i++) acc[i] = (f32x4){0.f,0.f,0.f,0.f};
  #pragma unroll
  for(int nt=0;nt<12;nt++){
    #pragma unroll
    for(int kk=0;kk<5;kk++){
      short8 Bf = *(const short8*)(Wb + (nt*16+l16)*168 + kk*32 + quad*8);
      acc[nt] = __builtin_amdgcn_mfma_f32_16x16x32_bf16(Af[kk], Bf, acc[nt], 0,0,0);
    }
  }
  #pragma unroll
  for(int nt=0;nt<12;nt++){
    int o = nt*16 + l16;
    #pragma unroll
    for(int r=0;r<4;r++){
      int tl = w*16 + quad*4 + r;
      int mg = t0 + tl;
      float val = acc[nt][r];
      if(o < 64)        qb[(size_t)mg*64 + o]        = f2b(val*sc2);
      else if(o < 128)  kb[(size_t)mg*64 + (o-64)]   = f2b(val);
      else              vfb[(size_t)mg*64 + (o-128)] = f2b(val);
    }
  }
  __syncthreads();
  #pragma unroll
  for(int nt=8;nt<12;nt++){
    int hd = (nt-8)*16 + l16;
    #pragma unroll
    for(int r=0;r<4;r++)
      VT[hd*72 + (w*16 + quad*4 + r)] = f2b(acc[nt][r]);
  }
  __syncthreads();
  {
    int b = t0 / N_, n0 = t0 - b*N_;
    const unsigned int* VT32 = (const unsigned int*)VT;
    unsigned int* vg = (unsigned int*)vtb + ((size_t)b*64)*(N_/2) + (n0>>1);
    #pragma unroll
    for(int rep=0;rep<8;rep++){
      int f = rep*256 + tid;
      int row = f>>5, c = f&31;
      vg[(size_t)row*(N_/2) + c] = VT32[row*36 + c];
    }
  }
}

// ---------------------------------------------------------------- K2: attention — R14: register-staged KV, zero main-loop barriers
// R2/R4 evidence: 43us at MfmaUtil 17 / VALU 28 / HBM 13 with BOTH occupancy fixes failing ->
// the stall is the staging structure (per-tile vmcnt + 2 s_barrier + LDS round-trip with 4-way
// bank conflicts) that chains all waves to the slowest load burst, ~12x per block.
// Fix (T14): per-wave KV frags are only 128B/lane/tile -> load global->VGPR directly (sigma/XOR
// swizzles fold into one-time base-pointer math), double-buffer K0/K1/V0/V1 in regs, prefetch
// 2 tiles ahead (~1200cyc distance). Main loop: NO barriers, NO LDS, waves fully independent.
// LDS kept only for the final w0/w1 merge. 2-wave blocks (R2-proven shape), grid 49x4x8.
__global__ __launch_bounds__(128,2) void k_attn(const unsigned short* __restrict__ qb,
                                                const unsigned short* __restrict__ kb,
                                                const unsigned short* __restrict__ vtb,
                                                unsigned short* __restrict__ Opart,
                                                float* __restrict__ lpart){
  __shared__ alignas(16) unsigned int L[4096];   // merge scratch only (16KB)
  __shared__ float Lr[128];
  int tid = threadIdx.x;
  int w = tid>>6, lane = tid&63;
  int h = lane>>5, l32 = lane&31;
  int qt = blockIdx.x, sp = blockIdx.y, b = blockIdx.z;
  int q0 = qt*64;
  int kv0 = (sp*49)>>2, kv1 = ((sp+1)*49)>>2;
  int nt = kv1 - kv0;                            // 12 or 13 (>=2 always)

  // Q B-frags (32x32x16): n=l32 -> q=q0+32qh+l32; k=8h+i -> hd=16kc+8h+i
  short8 Qf[2][4];
  {
    const unsigned short* qg = qb + ((size_t)b*N_ + q0)*64;
    #pragma unroll
    for(int qh=0;qh<2;qh++)
      #pragma unroll
      for(int kc=0;kc<4;kc++)
        Qf[qh][kc] = *(const short8*)(qg + (32*qh + l32)*64 + 16*kc + 8*h);
  }
  // Per-lane gather bases (swizzles folded in, one-time):
  // K: LDS row l32 used to hold global row 32w+sig(l32), data col chunk (2kc+h)*8 shorts.
  int sig32 = (l32 & 0x13) | ((l32&4)<<1) | ((l32&8)>>1);     // swap bits 2<->3 (involution)
  const unsigned short* kR = kb + ((size_t)b*N_ + (size_t)kv0*64 + 32*w + sig32)*64 + 8*h;
  // V^T: row (32*hdq + l32), col chunk (4w+c*2+h)*8 shorts within tile (tile col base kvt*64).
  const unsigned short* vR0 = vtb + (size_t)b*64*N_ + (size_t)l32*N_ + (size_t)kv0*64 + (4*w+h)*8;
  const unsigned short* vR1 = vR0 + (size_t)32*N_;

  // reg staging buffers: K[kc]; V: {hdq0c0, hdq0c1, hdq1c0, hdq1c1}
  short8 K0[4], K1[4], V0[4], V1[4];
#define LDK(DST, T) { const unsigned short* p_ = kR + (size_t)(T)*4096; \
    DST[0]=*(const short8*)(p_);    DST[1]=*(const short8*)(p_+16); \
    DST[2]=*(const short8*)(p_+32); DST[3]=*(const short8*)(p_+48); }
#define LDV(DST, T) { const unsigned short* p0_ = vR0 + (size_t)(T)*64; \
    const unsigned short* p1_ = vR1 + (size_t)(T)*64; \
    DST[0]=*(const short8*)(p0_); DST[1]=*(const short8*)(p0_+16); \
    DST[2]=*(const short8*)(p1_); DST[3]=*(const short8*)(p1_+16); }

  f32x16 O[2][2];
  #pragma unroll
  for(int qh=0;qh<2;qh++) for(int hdq=0;hdq<2;hdq++)
    #pragma unroll
    for(int r=0;r<16;r++) O[qh][hdq][r] = 0.f;
  float lracc[2][4];
  #pragma unroll
  for(int qh=0;qh<2;qh++)
    #pragma unroll
    for(int j=0;j<4;j++) lracc[qh][j] = 0.f;

  // prologue: tiles 0 and 1 into the two buffers (16 loads in flight)
  LDK(K0,0); LDV(V0,0);
  LDK(K1,1); LDV(V1,1);

  int i = 0;
#define TILESTEP(KC,VC) { \
    int kvt = kv0 + i; \
    _Pragma("unroll") \
    for(int qh=0;qh<2;qh++){ \
      f32x16 S; \
      _Pragma("unroll") \
      for(int r=0;r<16;r++) S[r] = 0.f; \
      _Pragma("unroll") \
      for(int kc=0;kc<4;kc++) \
        S = __builtin_amdgcn_mfma_f32_32x32x16_bf16(KC[kc], Qf[qh][kc], S, 0,0,0); \
      f32x16 E; \
      if(kvt == qt){ \
        int dref = 32*qh + l32 - 32*w - 8*h; \
        _Pragma("unroll") \
        for(int r=0;r<16;r++){ \
          int kvl = 16*((r>>3)&1) + 4*((r>>2)&1) + (r&3); \
          float pv = (kvl == dref) ? 0.f : __builtin_amdgcn_exp2f(S[r]); \
          E[r] = pv; lracc[qh][r&3] += pv; \
        } \
      } else { \
        _Pragma("unroll") \
        for(int r=0;r<16;r++){ \
          float pv = __builtin_amdgcn_exp2f(S[r]); \
          E[r] = pv; lracc[qh][r&3] += pv; \
        } \
      } \
      pk8 Pb0, Pb1; \
      Pb0.u = (u32x4){ pk2t(E[0],E[1]),   pk2t(E[2],E[3]), \
                       pk2t(E[4],E[5]),   pk2t(E[6],E[7]) }; \
      Pb1.u = (u32x4){ pk2t(E[8],E[9]),   pk2t(E[10],E[11]), \
                       pk2t(E[12],E[13]), pk2t(E[14],E[15]) }; \
      O[qh][0] = __builtin_amdgcn_mfma_f32_32x32x16_bf16(VC[0], Pb0.s, O[qh][0], 0,0,0); \
      O[qh][0] = __builtin_amdgcn_mfma_f32_32x32x16_bf16(VC[1], Pb1.s, O[qh][0], 0,0,0); \
      O[qh][1] = __builtin_amdgcn_mfma_f32_32x32x16_bf16(VC[2], Pb0.s, O[qh][1], 0,0,0); \
      O[qh][1] = __builtin_amdgcn_mfma_f32_32x32x16_bf16(VC[3], Pb1.s, O[qh][1], 0,0,0); \
    } \
    { int pf_ = i + 2; if(pf_ > nt-1) pf_ = nt-1;   /* clamp: redundant reload of last tile */ \
      LDK(KC, pf_); LDV(VC, pf_); } \
    __builtin_amdgcn_sched_barrier(0); \
    i++; }

  while(i + 2 <= nt){
    TILESTEP(K0,V0);
    TILESTEP(K1,V1);
  }
  if(i < nt){ TILESTEP(K0,V0); }   // odd nt tail (tile index even -> K0 parity correct)

#undef TILESTEP
#undef LDK
#undef LDV

  float lr[2];
  #pragma unroll
  for(int qh=0;qh<2;qh++)
    lr[qh] = (lracc[qh][0] + lracc[qh][1]) + (lracc[qh][2] + lracc[qh][3]);
  // merge the 2 waves' kv-half partials
  lr[0] += __shfl_xor(lr[0],32,64);
  lr[1] += __shfl_xor(lr[1],32,64);
  __syncthreads();
  if(w == 0){
    #pragma unroll
    for(int qh=0;qh<2;qh++)
      #pragma unroll
      for(int hdq=0;hdq<2;hdq++)
        #pragma unroll
        for(int r=0;r<16;r++)
          L[(qh*32 + hdq*16 + r)*64 + lane] = __float_as_uint(O[qh][hdq][r]);
    Lr[lane]      = lr[0];
    Lr[64 + lane] = lr[1];
  }
  __syncthreads();
  if(w == 1){
    #pragma unroll
    for(int qh=0;qh<2;qh++)
      #pragma unroll
      for(int hdq=0;hdq<2;hdq++)
        #pragma unroll
        for(int r=0;r<16;r++)
          O[qh][hdq][r] += __uint_as_float(L[(qh*32 + hdq*16 + r)*64 + lane]);
    float lt0 = lr[0] + Lr[lane];
    float lt1 = lr[1] + Lr[64 + lane];
    size_t lb = (size_t)sp*TOK_ + (size_t)b*N_ + q0;
    if(lane < 32){ lpart[lb + lane] = lt0; lpart[lb + 32 + lane] = lt1; }
    // transpose O^T -> [q][hd] bf16 in L (in-wave DS ordering: reads above precede writes)
    #pragma unroll
    for(int qh=0;qh<2;qh++){
      int q = 32*qh + l32;
      #pragma unroll
      for(int hdq=0;hdq<2;hdq++)
        #pragma unroll
        for(int k2=0;k2<8;k2++){
          int idx = 16*hdq + 4*(k2>>1) + 2*h + (k2&1);
          L[q*36 + idx] = pk2(O[qh][hdq][2*k2], O[qh][hdq][2*k2+1]);
        }
    }
    unsigned int* og = (unsigned int*)(Opart + ((size_t)sp*TOK_ + (size_t)b*N_ + q0)*64);
    #pragma unroll
    for(int rep=0;rep<8;rep++){
      int f = rep*64 + lane;
      int row = f>>3, c4 = f&7;
      *(u32x4*)(og + row*32 + c4*4) = *(const u32x4*)&L[row*36 + c4*4];
    }
  }
}

// ---------------------------------------------------------------- K3: merge + proj + residual(v) + LN2 + MLP + residual
__global__ __launch_bounds__(256) void k_mlp(const unsigned short* __restrict__ Opart,
                                             const float* __restrict__ lpart,
                                             const unsigned short* __restrict__ vfb,
                                             const float* __restrict__ projw,
                                             const float* __restrict__ fc1w,
                                             const float* __restrict__ fc2w,
                                             const float* __restrict__ projb,
                                             const float* __restrict__ n2w,
                                             const float* __restrict__ n2b,
                                             const float* __restrict__ fc1b,
                                             const float* __restrict__ fc2b,
                                             float* __restrict__ out){
  __shared__ alignas(16) unsigned short Ws[3][64*72];
  __shared__ alignas(16) unsigned short Xs[64*72];
  unsigned int* Xs32 = (unsigned int*)Xs;
  int tid = threadIdx.x;
  int w = tid>>6, lane = tid&63, quad = lane>>4, l16 = lane&15;
  int t0 = blockIdx.x*64;

  {
    #pragma unroll
    for(int rep=0;rep<2;rep++){
      int f = rep*256 + tid;
      int row = f>>3, c = f&7;
      int so = (row<<6) + (c<<3);          // f32 src offset, 16B-aligned
      f32x4 a0 = *(const f32x4*)(projw + so), b0 = *(const f32x4*)(projw + so + 4);
      f32x4 a1 = *(const f32x4*)(fc1w  + so), b1v = *(const f32x4*)(fc1w  + so + 4);
      f32x4 a2 = *(const f32x4*)(fc2w  + so), b2 = *(const f32x4*)(fc2w  + so + 4);
      *(u32x4*)((unsigned int*)Ws[0] + row*36 + c*4) =
        (u32x4){pk2(a0[0],a0[1]),pk2(a0[2],a0[3]),pk2(b0[0],b0[1]),pk2(b0[2],b0[3])};
      *(u32x4*)((unsigned int*)Ws[1] + row*36 + c*4) =
        (u32x4){pk2(a1[0],a1[1]),pk2(a1[2],a1[3]),pk2(b1v[0],b1v[1]),pk2(b1v[2],b1v[3])};
      *(u32x4*)((unsigned int*)Ws[2] + row*36 + c*4) =
        (u32x4){pk2(a2[0],a2[1]),pk2(a2[2],a2[3]),pk2(b2[0],b2[1]),pk2(b2[2],b2[3])};
    }
  }
  #pragma unroll
  for(int i=0;i<2;i++){
    int f = i*256 + tid;
    int row = f>>3, c = f&7;
    float lo[4] = {0,0,0,0}, hi[4] = {0,0,0,0};
    float lsum = 0.f;
    #pragma unroll
    for(int s=0;s<NSPLIT;s++){
      u32x4 a = *((const u32x4*)(Opart + ((size_t)s*TOK_ + t0)*64) + row*8 + c);
      #pragma unroll
      for(int k=0;k<4;k++){
        lo[k] += __uint_as_float(a[k]<<16);
        hi[k] += __uint_as_float(a[k] & 0xffff0000u);
      }
      lsum += lpart[(size_t)s*TOK_ + t0 + row];
    }
    float linv = 1.f/lsum;
    u32x4 o;
    #pragma unroll
    for(int k=0;k<4;k++) o[k] = pk2(lo[k]*linv, hi[k]*linv);
    *(u32x4*)&Xs32[row*36 + c*4] = o;
  }
  __syncthreads();

  short8 Af[2];
  #pragma unroll
  for(int kk=0;kk<2;kk++)
    Af[kk] = *(const short8*)(Xs + (w*16+l16)*72 + kk*32 + quad*8);
  f32x4 acc[4];
  #pragma unroll
  for(int i=0;i<4;i++) acc[i] = (f32x4){0.f,0.f,0.f,0.f};
  #pragma unroll
  for(int jt=0;jt<4;jt++)
    #pragma unroll
    for(int kk=0;kk<2;kk++){
      short8 Bf = *(const short8*)(Ws[0] + (jt*16+l16)*72 + kk*32 + quad*8);
      acc[jt] = __builtin_amdgcn_mfma_f32_16x16x32_bf16(Af[kk], Bf, acc[jt], 0,0,0);
    }
  float xa[4][4];
  #pragma unroll
  for(int jt=0;jt<4;jt++){
    int col = jt*16 + l16;
    float pb = projb[col];
    #pragma unroll
    for(int r=0;r<4;r++){
      int tg = t0 + w*16 + quad*4 + r;
      xa[jt][r] = acc[jt][r] + pb + b2f(vfb[(size_t)tg*64 + col]);
    }
  }
  #pragma unroll
  for(int r=0;r<4;r++){
    float s = 0.f, sq = 0.f;
    #pragma unroll
    for(int jt=0;jt<4;jt++){ s += xa[jt][r]; sq += xa[jt][r]*xa[jt][r]; }
    s  += __shfl_xor(s,1,64);  s  += __shfl_xor(s,2,64);
    s  += __shfl_xor(s,4,64);  s  += __shfl_xor(s,8,64);
    sq += __shfl_xor(sq,1,64); sq += __shfl_xor(sq,2,64);
    sq += __shfl_xor(sq,4,64); sq += __shfl_xor(sq,8,64);
    float mu = s*(1.f/64.f);
    float var = sq*(1.f/64.f) - mu*mu;
    float rstd = rsqrtf(var + 1e-5f);
    #pragma unroll
    for(int jt=0;jt<4;jt++){
      int col = jt*16 + l16;
      Xs[(w*16+quad*4+r)*72 + col] = f2b((xa[jt][r]-mu)*rstd*n2w[col] + n2b[col]);
    }
  }
  #pragma unroll
  for(int kk=0;kk<2;kk++)
    Af[kk] = *(const short8*)(Xs + (w*16+l16)*72 + kk*32 + quad*8);
  f32x4 acc2[4];
  #pragma unroll
  for(int i=0;i<4;i++) acc2[i] = (f32x4){0.f,0.f,0.f,0.f};
  #pragma unroll
  for(int jt=0;jt<4;jt++)
    #pragma unroll
    for(int kk=0;kk<2;kk++){
      short8 Bf = *(const short8*)(Ws[1] + (jt*16+l16)*72 + kk*32 + quad*8);
      acc2[jt] = __builtin_amdgcn_mfma_f32_16x16x32_bf16(Af[kk], Bf, acc2[jt], 0,0,0);
    }
  #pragma unroll
  for(int jt=0;jt<4;jt++){
    int col = jt*16 + l16;
    float fb = fc1b[col];
    #pragma unroll
    for(int r=0;r<4;r++){
      float g = acc2[jt][r] + fb;
      float z = g*0.70710678118f;
      float az = fabsf(z);
      float t = 1.f/(1.f + 0.3275911f*az);
      float poly = ((((1.061405429f*t - 1.453152027f)*t + 1.421413741f)*t - 0.284496736f)*t + 0.254829592f)*t;
      float er = 1.f - poly*__builtin_amdgcn_exp2f(-az*az*1.44269504089f);
      er = (z < 0.f) ? -er : er;
      Xs[(w*16+quad*4+r)*72 + col] = f2b(0.5f*g*(1.f + er));
    }
  }
  #pragma unroll
  for(int kk=0;kk<2;kk++)
    Af[kk] = *(const short8*)(Xs + (w*16+l16)*72 + kk*32 + quad*8);
  f32x4 acc3[4];
  #pragma unroll
  for(int i=0;i<4;i++) acc3[i] = (f32x4){0.f,0.f,0.f,0.f};
  #pragma unroll
  for(int jt=0;jt<4;jt++)
    #pragma unroll
    for(int kk=0;kk<2;kk++){
      short8 Bf = *(const short8*)(Ws[2] + (jt*16+l16)*72 + kk*32 + quad*8);
      acc3[jt] = __builtin_amdgcn_mfma_f32_16x16x32_bf16(Af[kk], Bf, acc3[jt], 0,0,0);
    }
  #pragma unroll
  for(int jt=0;jt<4;jt++){
    int col = jt*16 + l16;
    float ob2 = fc2b[col];
    #pragma unroll
    for(int r=0;r<4;r++){
      int tg = t0 + w*16 + quad*4 + r;
      out[(size_t)tg*64 + col] = xa[jt][r] + acc3[jt][r] + ob2;
    }
  }
}

// ---------------------------------------------------------------- launch
extern "C" void kernel_launch(void* const* d_in, const int* in_sizes, int n_in,
                              void* d_out, int out_size, void* d_ws, size_t ws_size,
                              hipStream_t stream){
  const float* x     = (const float*)d_in[0];
  const float* n1w   = (const float*)d_in[1];
  const float* n1b   = (const float*)d_in[2];
  const float* qkvw  = (const float*)d_in[3];
  const float* scale = (const float*)d_in[4];
  const float* projw = (const float*)d_in[5];
  const float* projb = (const float*)d_in[6];
  const float* n2w   = (const float*)d_in[7];
  const float* n2b   = (const float*)d_in[8];
  const float* fc1w  = (const float*)d_in[9];
  const float* fc1b  = (const float*)d_in[10];
  const float* fc2w  = (const float*)d_in[11];
  const float* fc2b  = (const float*)d_in[12];

  char* base = (char*)d_ws;
  unsigned short* qb  = (unsigned short*)(base + 0);          //  3211264
  unsigned short* kb  = (unsigned short*)(base + 3211264);    //  3211264
  unsigned short* vtb = (unsigned short*)(base + 6422528);    //  3211264
  unsigned short* vfb = (unsigned short*)(base + 9633792);    //  3211264
  unsigned short* Op  = (unsigned short*)(base + 12845056);   // 12845056 (4 splits bf16)
  float*          lp  = (float*)(base + 25690112);            //   401408  -> total 26091520

  hipLaunchKernelGGL(k_qkv,  dim3(TOK_/64),    dim3(256), 0, stream,
                     x, n1w, n1b, qkvw, scale, qb, kb, vtb, vfb);
  hipLaunchKernelGGL(k_attn, dim3(49,NSPLIT,8), dim3(128), 0, stream, qb, kb, vtb, Op, lp);
  hipLaunchKernelGGL(k_mlp,  dim3(TOK_/64),    dim3(256), 0, stream, Op, lp, vfb,
                     projw, fc1w, fc2w, projb, n2w, n2b, fc1b, fc2b, (float*)d_out);
}

// Round 6
// 153.019 us; speedup vs baseline: 1.0526x; 1.0526x over previous
//
#include <hip/hip_runtime.h>
#include <math.h>
#include <stdint.h>

#define B_    8
#define N_    3136
#define DIM_  147
#define KP_   160
#define TOK_  (B_*N_)      // 25088
#define QKV3_ 192
#define NSPLIT 4

typedef __attribute__((ext_vector_type(4)))  float f32x4;
typedef __attribute__((ext_vector_type(16))) float f32x16;
typedef __attribute__((ext_vector_type(4)))  unsigned int u32x4;
typedef __attribute__((ext_vector_type(2)))  unsigned int u32x2;
typedef __attribute__((ext_vector_type(8)))  short short8;
typedef float f32x4u __attribute__((ext_vector_type(4), aligned(4)));  // 4B-aligned vector load
typedef union { short8 s; u32x4 u; } pk8;

static __device__ __forceinline__ unsigned short f2b(float f){
  unsigned int u = __float_as_uint(f);
  u += 0x7fffu + ((u>>16)&1u);          // RNE
  return (unsigned short)(u>>16);
}
static __device__ __forceinline__ unsigned int pk2(float a, float b){   // RNE pack
  return ((unsigned int)f2b(b)<<16) | (unsigned int)f2b(a);
}
static __device__ __forceinline__ unsigned int pk2t(float a, float b){  // trunc pack (P only)
  return (__float_as_uint(b) & 0xffff0000u) | (__float_as_uint(a)>>16);
}
static __device__ __forceinline__ float b2f(unsigned short s){
  return __uint_as_float(((unsigned int)s)<<16);
}

// async global->LDS, 16 B per lane; LDS dest = uniform base + lane*16
#define GLD16(gp, lp) __builtin_amdgcn_global_load_lds( \
    reinterpret_cast<const uint32_t __attribute__((address_space(1)))*>(reinterpret_cast<uintptr_t>(gp)), \
    reinterpret_cast<uint32_t __attribute__((address_space(3)))*>(reinterpret_cast<uintptr_t>(lp)), \
    16, 0, 0)

// ---------------------------------------------------------------- K1: fused LN1 + QKV GEMM
__global__ __launch_bounds__(256) void k_qkv(const float* __restrict__ x,
                                             const float* __restrict__ w1,
                                             const float* __restrict__ b1,
                                             const float* __restrict__ qkvw,
                                             const float* __restrict__ scale,
                                             unsigned short* __restrict__ qb,
                                             unsigned short* __restrict__ kb,
                                             unsigned short* __restrict__ vtb,
                                             unsigned short* __restrict__ vfb){
  __shared__ alignas(16) unsigned short Wb[192*168];  // 64512 B; aliased by A_ and VT
  unsigned short* A_ = Wb;
  unsigned short* VT = Wb;
  int tid = threadIdx.x;
  int w = tid>>6, lane = tid&63, quad = lane>>4, l16 = lane&15;
  int t0 = blockIdx.x*64;
  float sc2 = scale[0] * 1.44269504089f;

  #pragma unroll
  for(int half=0; half<2; half++){
    int g = half*32 + (tid>>3), e = tid&7;
    const float* xr = x + (size_t)(t0+g)*147;
    f32x4u xv[5];
    float s = 0.f, sq = 0.f;
    #pragma unroll
    for(int j=0;j<5;j++){
      int k = e + 8*j;                      // chunk index, cols 4k..4k+3
      int keff = (k > 36) ? 36 : k;         // clamp addr (masked lanes reuse chunk 36)
      f32x4u v = *(const f32x4u*)(xr + 4*keff);
      if(j == 4){                           // k in [32,39]: mask tail
        v[0] = (k<=36) ? v[0] : 0.f;
        v[1] = (k<=36) ? v[1] : 0.f;
        v[2] = (k<=36) ? v[2] : 0.f;
        v[3] = (k< 36) ? v[3] : 0.f;        // col 147 invalid at k==36
      }
      xv[j] = v;
      s  += (v[0]+v[1]) + (v[2]+v[3]);
      sq += (v[0]*v[0]+v[1]*v[1]) + (v[2]*v[2]+v[3]*v[3]);
    }
    s  += __shfl_xor(s,1,64);  s  += __shfl_xor(s,2,64);  s  += __shfl_xor(s,4,64);
    sq += __shfl_xor(sq,1,64); sq += __shfl_xor(sq,2,64); sq += __shfl_xor(sq,4,64);
    float mean = s*(1.f/147.f);
    float var  = sq*(1.f/147.f) - mean*mean;
    float rstd = rsqrtf(var + 1e-5f);
    #pragma unroll
    for(int j=0;j<5;j++){
      int k = e + 8*j;
      unsigned int lo = 0u, hi = 0u;
      if(k <= 36){
        int c0 = 4*k;
        int c3 = (k==36) ? 146 : c0+3;      // don't read w1/b1 past 146
        float y0 = (xv[j][0]-mean)*rstd*w1[c0]   + b1[c0];
        float y1 = (xv[j][1]-mean)*rstd*w1[c0+1] + b1[c0+1];
        float y2 = (xv[j][2]-mean)*rstd*w1[c0+2] + b1[c0+2];
        float y3 = (xv[j][3]-mean)*rstd*w1[c3]   + b1[c3];
        if(k == 36) y3 = 0.f;               // col 147 -> 0 (K padding)
        lo = pk2(y0,y1); hi = pk2(y2,y3);
      }
      *(u32x2*)(A_ + g*168 + 4*k) = (u32x2){lo,hi};   // k>36 lanes zero cols 148..159
    }
  }
  __syncthreads();
  short8 Af[5];
  #pragma unroll
  for(int kk=0;kk<5;kk++)
    Af[kk] = *(const short8*)(A_ + (w*16+l16)*168 + kk*32 + quad*8);
  __syncthreads();
  {
    // stage qkv weights: convert f32 -> bf16 inline
    unsigned int* dst = (unsigned int*)Wb;
    #pragma unroll
    for(int rep=0; rep<15; rep++){
      int idx = rep*256 + tid;
      int row = idx/20, c = idx - row*20;
      u32x4 o = (u32x4){0u,0u,0u,0u};
      if(c < 19){
        const float* sp = qkvw + row*147 + c*8;
        f32x4u a = *(const f32x4u*)sp;
        o[0] = pk2(a[0],a[1]);
        if(c < 18){
          f32x4u bv = *(const f32x4u*)(sp+4);
          o[1] = pk2(a[2],a[3]);
          o[2] = pk2(bv[0],bv[1]);
          o[3] = pk2(bv[2],bv[3]);
        } else {
          o[1] = pk2(a[2],0.f);             // col 147 of row = next row's elem -> masked
        }
      }
      *(u32x4*)(dst + row*84 + c*4) = o;
    }
  }
  __syncthreads();
  f32x4 acc[12];
  #pragma unroll
  for(int i=0;i<12;i++) acc[i] = (f32x4){0.f,0.f,0.f,0.f};
  #pragma unroll
  for(int nt=0;nt<12;nt++){
    #pragma unroll
    for(int kk=0;kk<5;kk++){
      short8 Bf = *(const short8*)(Wb + (nt*16+l16)*168 + kk*32 + quad*8);
      acc[nt] = __builtin_amdgcn_mfma_f32_16x16x32_bf16(Af[kk], Bf, acc[nt], 0,0,0);
    }
  }
  #pragma unroll
  for(int nt=0;nt<12;nt++){
    int o = nt*16 + l16;
    #pragma unroll
    for(int r=0;r<4;r++){
      int tl = w*16 + quad*4 + r;
      int mg = t0 + tl;
      float val = acc[nt][r];
      if(o < 64)        qb[(size_t)mg*64 + o]        = f2b(val*sc2);
      else if(o < 128)  kb[(size_t)mg*64 + (o-64)]   = f2b(val);
      else              vfb[(size_t)mg*64 + (o-128)] = f2b(val);
    }
  }
  __syncthreads();
  #pragma unroll
  for(int nt=8;nt<12;nt++){
    int hd = (nt-8)*16 + l16;
    #pragma unroll
    for(int r=0;r<4;r++)
      VT[hd*72 + (w*16 + quad*4 + r)] = f2b(acc[nt][r]);
  }
  __syncthreads();
  {
    int b = t0 / N_, n0 = t0 - b*N_;
    const unsigned int* VT32 = (const unsigned int*)VT;
    unsigned int* vg = (unsigned int*)vtb + ((size_t)b*64)*(N_/2) + (n0>>1);
    #pragma unroll
    for(int rep=0;rep<8;rep++){
      int f = rep*256 + tid;
      int row = f>>5, c = f&31;
      vg[(size_t)row*(N_/2) + c] = VT32[row*36 + c];
    }
  }
}

// ---------------------------------------------------------------- K2: attention — R15: GLD16 staging into WAVE-PRIVATE LDS, zero barriers
// R5 lesson: per-lane reg gathers (32-way divergence/instr) are 4x the L2 transactions of GLD16 ->
// slower than the barrier cost they removed. R2/R4 lesson: barriers chain waves to the slowest
// load burst. Fix: keep coalesced GLD16 (1KB/instr) but make ALL staged data wave-private --
// K was already (4KB half); V now staged per-wave in full (8KB, same 128B-row XOR layout).
// Main loop: NO s_barrier; only per-wave counted s_waitcnt vmcnt(12), dbuf 1 tile ahead.
// WAR is wave-local: ds_reads of a buffer drain (compiler lgkmcnt) before next GLD16 to it issues.
// Cost: V staged 2x/block (L2-resident, ~23TB/s agg worst case < 34.5 ceiling).
// LDS 2x2x12KB=48KB -> 3 blocks/CU = 6 waves/CU, fully decoupled.
__global__ __launch_bounds__(128,2) void k_attn(const unsigned short* __restrict__ qb,
                                                const unsigned short* __restrict__ kb,
                                                const unsigned short* __restrict__ vtb,
                                                unsigned short* __restrict__ Opart,
                                                float* __restrict__ lpart){
  __shared__ alignas(16) char LB[49152];   // [2 buf][2 wave][12KB: K 4KB | V 8KB]; merge reuse
  __shared__ float Lr[128];
  int tid = threadIdx.x;
  int w = tid>>6, lane = tid&63;
  int h = lane>>5, l32 = lane&31, l7 = l32&7;
  int qt = blockIdx.x, sp = blockIdx.y, b = blockIdx.z;
  int q0 = qt*64;
  int kv0 = (sp*49)>>2, kv1 = ((sp+1)*49)>>2;
  int nt = kv1 - kv0;

  // Q B-frags (32x32x16): n=l32 -> q=q0+32qh+l32; k=8h+i -> hd=16kc+8h+i
  short8 Qf[2][4];
  {
    const unsigned short* qg = qb + ((size_t)b*N_ + q0)*64;
    #pragma unroll
    for(int qh=0;qh<2;qh++)
      #pragma unroll
      for(int kc=0;kc<4;kc++)
        Qf[qh][kc] = *(const short8*)(qg + (32*qh + l32)*64 + 16*kc + 8*h);
  }
  // staging offsets: K = wave's kv half (sigma'd rows, XOR cols); V = FULL 64 hd rows (XOR cols)
  int koffG[4], voffG[8];
  {
    int pl = lane>>3, cl = lane&7;
    #pragma unroll
    for(int rr=0;rr<4;rr++){
      int p = rr*8 + pl;
      int sig = (p & 0x13) | ((p&4)<<1) | ((p&8)>>1);   // swap bits 2<->3
      koffG[rr] = (32*w + sig)*128 + (cl ^ (p&7))*16;   // K: sigma'd row, byte col
    }
    #pragma unroll
    for(int rr=0;rr<8;rr++){
      int p = rr*8 + pl;                                 // hd row 0..63
      voffG[rr] = p*(N_*2) + (cl ^ (p&7))*16;            // V^T: plain hd row
    }
  }
  const char* kBase = (const char*)kb + (size_t)b*N_*128;
  const char* vBase = (const char*)vtb + (size_t)b*64*(size_t)(N_*2);
  char* wbuf0 = LB + w*12288;            // this wave's buffer 0
  char* wbuf1 = LB + 24576 + w*12288;    // this wave's buffer 1

#define STAGE(bufp, T) { \
    const char* kT_ = kBase + (size_t)(T)*8192; \
    const char* vT_ = vBase + (size_t)(T)*128; \
    _Pragma("unroll") \
    for(int rr=0;rr<4;rr++) GLD16(kT_ + koffG[rr], (bufp) + rr*1024); \
    _Pragma("unroll") \
    for(int rr=0;rr<8;rr++) GLD16(vT_ + voffG[rr], (bufp) + 4096 + rr*1024); }

  f32x16 O[2][2];
  #pragma unroll
  for(int qh=0;qh<2;qh++) for(int hdq=0;hdq<2;hdq++)
    #pragma unroll
    for(int r=0;r<16;r++) O[qh][hdq][r] = 0.f;
  float lracc[2][4];
  #pragma unroll
  for(int qh=0;qh<2;qh++)
    #pragma unroll
    for(int j=0;j<4;j++) lracc[qh][j] = 0.f;

  STAGE(wbuf0, kv0);                     // prologue: tile 0 -> buf0 (12 loads in flight)

  for(int i=0;i<nt;i++){
    int kvt = kv0 + i;
    char* cb = (i&1) ? wbuf1 : wbuf0;
    char* nb = (i&1) ? wbuf0 : wbuf1;
    if(i+1 < nt){
      STAGE(nb, kvt+1);                  // 24 outstanding max
      asm volatile("s_waitcnt vmcnt(12)" ::: "memory");   // tile i's 12 done; i+1 in flight
    } else {
      asm volatile("s_waitcnt vmcnt(0)" ::: "memory");
    }
    __builtin_amdgcn_sched_barrier(0);   // pin: no ds_read above the wait

    const unsigned short* Kh = (const unsigned short*)cb;
    const unsigned short* Vh = (const unsigned short*)(cb + 4096);

    short8 Kf[4];
    #pragma unroll
    for(int kc=0;kc<4;kc++)
      Kf[kc] = *(const short8*)(Kh + l32*64 + (((2*kc+h) ^ l7)&7)*8);
    #pragma unroll
    for(int qh=0;qh<2;qh++){
      f32x16 S;
      #pragma unroll
      for(int r=0;r<16;r++) S[r] = 0.f;
      #pragma unroll
      for(int kc=0;kc<4;kc++)
        S = __builtin_amdgcn_mfma_f32_32x32x16_bf16(Kf[kc], Qf[qh][kc], S, 0,0,0);
      f32x16 E;
      if(kvt == qt){                     // diagonal tile (block-uniform branch)
        int dref = 32*qh + l32 - 32*w - 8*h;
        #pragma unroll
        for(int r=0;r<16;r++){
          int kvl = 16*((r>>3)&1) + 4*((r>>2)&1) + (r&3);
          float pv = (kvl == dref) ? 0.f : __builtin_amdgcn_exp2f(S[r]);
          E[r] = pv; lracc[qh][r&3] += pv;
        }
      } else {
        #pragma unroll
        for(int r=0;r<16;r++){
          float pv = __builtin_amdgcn_exp2f(S[r]);
          E[r] = pv; lracc[qh][r&3] += pv;
        }
      }
      pk8 Pb0, Pb1;
      Pb0.u = (u32x4){ pk2t(E[0],E[1]),   pk2t(E[2],E[3]),
                       pk2t(E[4],E[5]),   pk2t(E[6],E[7]) };
      Pb1.u = (u32x4){ pk2t(E[8],E[9]),   pk2t(E[10],E[11]),
                       pk2t(E[12],E[13]), pk2t(E[14],E[15]) };
      #pragma unroll
      for(int hdq=0;hdq<2;hdq++){
        short8 Vf0 = *(const short8*)(Vh + (32*hdq + l32)*64 + (((4*w + h) ^ l7)&7)*8);
        short8 Vf1 = *(const short8*)(Vh + (32*hdq + l32)*64 + (((4*w + 2 + h) ^ l7)&7)*8);
        O[qh][hdq] = __builtin_amdgcn_mfma_f32_32x32x16_bf16(Vf0, Pb0.s, O[qh][hdq], 0,0,0);
        O[qh][hdq] = __builtin_amdgcn_mfma_f32_32x32x16_bf16(Vf1, Pb1.s, O[qh][hdq], 0,0,0);
      }
    }
    __builtin_amdgcn_sched_barrier(0);   // iteration boundary: keep GLD16(next) after these reads
  }
#undef STAGE

  float lr[2];
  #pragma unroll
  for(int qh=0;qh<2;qh++)
    lr[qh] = (lracc[qh][0] + lracc[qh][1]) + (lracc[qh][2] + lracc[qh][3]);
  // merge the 2 waves' kv-half partials
  lr[0] += __shfl_xor(lr[0],32,64);
  lr[1] += __shfl_xor(lr[1],32,64);
  unsigned int* L = (unsigned int*)LB;   // merge scratch (first 16KB)
  __syncthreads();
  if(w == 0){
    #pragma unroll
    for(int qh=0;qh<2;qh++)
      #pragma unroll
      for(int hdq=0;hdq<2;hdq++)
        #pragma unroll
        for(int r=0;r<16;r++)
          L[(qh*32 + hdq*16 + r)*64 + lane] = __float_as_uint(O[qh][hdq][r]);
    Lr[lane]      = lr[0];
    Lr[64 + lane] = lr[1];
  }
  __syncthreads();
  if(w == 1){
    #pragma unroll
    for(int qh=0;qh<2;qh++)
      #pragma unroll
      for(int hdq=0;hdq<2;hdq++)
        #pragma unroll
        for(int r=0;r<16;r++)
          O[qh][hdq][r] += __uint_as_float(L[(qh*32 + hdq*16 + r)*64 + lane]);
    float lt0 = lr[0] + Lr[lane];
    float lt1 = lr[1] + Lr[64 + lane];
    size_t lb = (size_t)sp*TOK_ + (size_t)b*N_ + q0;
    if(lane < 32){ lpart[lb + lane] = lt0; lpart[lb + 32 + lane] = lt1; }
    // transpose O^T -> [q][hd] bf16 in L (in-wave DS ordering: reads above precede writes)
    #pragma unroll
    for(int qh=0;qh<2;qh++){
      int q = 32*qh + l32;
      #pragma unroll
      for(int hdq=0;hdq<2;hdq++)
        #pragma unroll
        for(int k2=0;k2<8;k2++){
          int idx = 16*hdq + 4*(k2>>1) + 2*h + (k2&1);
          L[q*36 + idx] = pk2(O[qh][hdq][2*k2], O[qh][hdq][2*k2+1]);
        }
    }
    unsigned int* og = (unsigned int*)(Opart + ((size_t)sp*TOK_ + (size_t)b*N_ + q0)*64);
    #pragma unroll
    for(int rep=0;rep<8;rep++){
      int f = rep*64 + lane;
      int row = f>>3, c4 = f&7;
      *(u32x4*)(og + row*32 + c4*4) = *(const u32x4*)&L[row*36 + c4*4];
    }
  }
}

// ---------------------------------------------------------------- K3: merge + proj + residual(v) + LN2 + MLP + residual
__global__ __launch_bounds__(256) void k_mlp(const unsigned short* __restrict__ Opart,
                                             const float* __restrict__ lpart,
                                             const unsigned short* __restrict__ vfb,
                                             const float* __restrict__ projw,
                                             const float* __restrict__ fc1w,
                                             const float* __restrict__ fc2w,
                                             const float* __restrict__ projb,
                                             const float* __restrict__ n2w,
                                             const float* __restrict__ n2b,
                                             const float* __restrict__ fc1b,
                                             const float* __restrict__ fc2b,
                                             float* __restrict__ out){
  __shared__ alignas(16) unsigned short Ws[3][64*72];
  __shared__ alignas(16) unsigned short Xs[64*72];
  unsigned int* Xs32 = (unsigned int*)Xs;
  int tid = threadIdx.x;
  int w = tid>>6, lane = tid&63, quad = lane>>4, l16 = lane&15;
  int t0 = blockIdx.x*64;

  {
    #pragma unroll
    for(int rep=0;rep<2;rep++){
      int f = rep*256 + tid;
      int row = f>>3, c = f&7;
      int so = (row<<6) + (c<<3);          // f32 src offset, 16B-aligned
      f32x4 a0 = *(const f32x4*)(projw + so), b0 = *(const f32x4*)(projw + so + 4);
      f32x4 a1 = *(const f32x4*)(fc1w  + so), b1v = *(const f32x4*)(fc1w  + so + 4);
      f32x4 a2 = *(const f32x4*)(fc2w  + so), b2 = *(const f32x4*)(fc2w  + so + 4);
      *(u32x4*)((unsigned int*)Ws[0] + row*36 + c*4) =
        (u32x4){pk2(a0[0],a0[1]),pk2(a0[2],a0[3]),pk2(b0[0],b0[1]),pk2(b0[2],b0[3])};
      *(u32x4*)((unsigned int*)Ws[1] + row*36 + c*4) =
        (u32x4){pk2(a1[0],a1[1]),pk2(a1[2],a1[3]),pk2(b1v[0],b1v[1]),pk2(b1v[2],b1v[3])};
      *(u32x4*)((unsigned int*)Ws[2] + row*36 + c*4) =
        (u32x4){pk2(a2[0],a2[1]),pk2(a2[2],a2[3]),pk2(b2[0],b2[1]),pk2(b2[2],b2[3])};
    }
  }
  #pragma unroll
  for(int i=0;i<2;i++){
    int f = i*256 + tid;
    int row = f>>3, c = f&7;
    float lo[4] = {0,0,0,0}, hi[4] = {0,0,0,0};
    float lsum = 0.f;
    #pragma unroll
    for(int s=0;s<NSPLIT;s++){
      u32x4 a = *((const u32x4*)(Opart + ((size_t)s*TOK_ + t0)*64) + row*8 + c);
      #pragma unroll
      for(int k=0;k<4;k++){
        lo[k] += __uint_as_float(a[k]<<16);
        hi[k] += __uint_as_float(a[k] & 0xffff0000u);
      }
      lsum += lpart[(size_t)s*TOK_ + t0 + row];
    }
    float linv = 1.f/lsum;
    u32x4 o;
    #pragma unroll
    for(int k=0;k<4;k++) o[k] = pk2(lo[k]*linv, hi[k]*linv);
    *(u32x4*)&Xs32[row*36 + c*4] = o;
  }
  __syncthreads();

  short8 Af[2];
  #pragma unroll
  for(int kk=0;kk<2;kk++)
    Af[kk] = *(const short8*)(Xs + (w*16+l16)*72 + kk*32 + quad*8);
  f32x4 acc[4];
  #pragma unroll
  for(int i=0;i<4;i++) acc[i] = (f32x4){0.f,0.f,0.f,0.f};
  #pragma unroll
  for(int jt=0;jt<4;jt++)
    #pragma unroll
    for(int kk=0;kk<2;kk++){
      short8 Bf = *(const short8*)(Ws[0] + (jt*16+l16)*72 + kk*32 + quad*8);
      acc[jt] = __builtin_amdgcn_mfma_f32_16x16x32_bf16(Af[kk], Bf, acc[jt], 0,0,0);
    }
  float xa[4][4];
  #pragma unroll
  for(int jt=0;jt<4;jt++){
    int col = jt*16 + l16;
    float pb = projb[col];
    #pragma unroll
    for(int r=0;r<4;r++){
      int tg = t0 + w*16 + quad*4 + r;
      xa[jt][r] = acc[jt][r] + pb + b2f(vfb[(size_t)tg*64 + col]);
    }
  }
  #pragma unroll
  for(int r=0;r<4;r++){
    float s = 0.f, sq = 0.f;
    #pragma unroll
    for(int jt=0;jt<4;jt++){ s += xa[jt][r]; sq += xa[jt][r]*xa[jt][r]; }
    s  += __shfl_xor(s,1,64);  s  += __shfl_xor(s,2,64);
    s  += __shfl_xor(s,4,64);  s  += __shfl_xor(s,8,64);
    sq += __shfl_xor(sq,1,64); sq += __shfl_xor(sq,2,64);
    sq += __shfl_xor(sq,4,64); sq += __shfl_xor(sq,8,64);
    float mu = s*(1.f/64.f);
    float var = sq*(1.f/64.f) - mu*mu;
    float rstd = rsqrtf(var + 1e-5f);
    #pragma unroll
    for(int jt=0;jt<4;jt++){
      int col = jt*16 + l16;
      Xs[(w*16+quad*4+r)*72 + col] = f2b((xa[jt][r]-mu)*rstd*n2w[col] + n2b[col]);
    }
  }
  #pragma unroll
  for(int kk=0;kk<2;kk++)
    Af[kk] = *(const short8*)(Xs + (w*16+l16)*72 + kk*32 + quad*8);
  f32x4 acc2[4];
  #pragma unroll
  for(int i=0;i<4;i++) acc2[i] = (f32x4){0.f,0.f,0.f,0.f};
  #pragma unroll
  for(int jt=0;jt<4;jt++)
    #pragma unroll
    for(int kk=0;kk<2;kk++){
      short8 Bf = *(const short8*)(Ws[1] + (jt*16+l16)*72 + kk*32 + quad*8);
      acc2[jt] = __builtin_amdgcn_mfma_f32_16x16x32_bf16(Af[kk], Bf, acc2[jt], 0,0,0);
    }
  #pragma unroll
  for(int jt=0;jt<4;jt++){
    int col = jt*16 + l16;
    float fb = fc1b[col];
    #pragma unroll
    for(int r=0;r<4;r++){
      float g = acc2[jt][r] + fb;
      float z = g*0.70710678118f;
      float az = fabsf(z);
      float t = 1.f/(1.f + 0.3275911f*az);
      float poly = ((((1.061405429f*t - 1.453152027f)*t + 1.421413741f)*t - 0.284496736f)*t + 0.254829592f)*t;
      float er = 1.f - poly*__builtin_amdgcn_exp2f(-az*az*1.44269504089f);
      er = (z < 0.f) ? -er : er;
      Xs[(w*16+quad*4+r)*72 + col] = f2b(0.5f*g*(1.f + er));
    }
  }
  #pragma unroll
  for(int kk=0;kk<2;kk++)
    Af[kk] = *(const short8*)(Xs + (w*16+l16)*72 + kk*32 + quad*8);
  f32x4 acc3[4];
  #pragma unroll
  for(int i=0;i<4;i++) acc3[i] = (f32x4){0.f,0.f,0.f,0.f};
  #pragma unroll
  for(int jt=0;jt<4;jt++)
    #pragma unroll
    for(int kk=0;kk<2;kk++){
      short8 Bf = *(const short8*)(Ws[2] + (jt*16+l16)*72 + kk*32 + quad*8);
      acc3[jt] = __builtin_amdgcn_mfma_f32_16x16x32_bf16(Af[kk], Bf, acc3[jt], 0,0,0);
    }
  #pragma unroll
  for(int jt=0;jt<4;jt++){
    int col = jt*16 + l16;
    float ob2 = fc2b[col];
    #pragma unroll
    for(int r=0;r<4;r++){
      int tg = t0 + w*16 + quad*4 + r;
      out[(size_t)tg*64 + col] = xa[jt][r] + acc3[jt][r] + ob2;
    }
  }
}

// ---------------------------------------------------------------- launch
extern "C" void kernel_launch(void* const* d_in, const int* in_sizes, int n_in,
                              void* d_out, int out_size, void* d_ws, size_t ws_size,
                              hipStream_t stream){
  const float* x     = (const float*)d_in[0];
  const float* n1w   = (const float*)d_in[1];
  const float* n1b   = (const float*)d_in[2];
  const float* qkvw  = (const float*)d_in[3];
  const float* scale = (const float*)d_in[4];
  const float* projw = (const float*)d_in[5];
  const float* projb = (const float*)d_in[6];
  const float* n2w   = (const float*)d_in[7];
  const float* n2b   = (const float*)d_in[8];
  const float* fc1w  = (const float*)d_in[9];
  const float* fc1b  = (const float*)d_in[10];
  const float* fc2w  = (const float*)d_in[11];
  const float* fc2b  = (const float*)d_in[12];

  char* base = (char*)d_ws;
  unsigned short* qb  = (unsigned short*)(base + 0);          //  3211264
  unsigned short* kb  = (unsigned short*)(base + 3211264);    //  3211264
  unsigned short* vtb = (unsigned short*)(base + 6422528);    //  3211264
  unsigned short* vfb = (unsigned short*)(base + 9633792);    //  3211264
  unsigned short* Op  = (unsigned short*)(base + 12845056);   // 12845056 (4 splits bf16)
  float*          lp  = (float*)(base + 25690112);            //   401408  -> total 26091520

  hipLaunchKernelGGL(k_qkv,  dim3(TOK_/64),    dim3(256), 0, stream,
                     x, n1w, n1b, qkvw, scale, qb, kb, vtb, vfb);
  hipLaunchKernelGGL(k_attn, dim3(49,NSPLIT,8), dim3(128), 0, stream, qb, kb, vtb, Op, lp);
  hipLaunchKernelGGL(k_mlp,  dim3(TOK_/64),    dim3(256), 0, stream, Op, lp, vfb,
                     projw, fc1w, fc2w, projb, n2w, n2b, fc1b, fc2b, (float*)d_out);
}

// Round 7
// 143.726 us; speedup vs baseline: 1.1206x; 1.0647x over previous
//
#include <hip/hip_runtime.h>
#include <math.h>
#include <stdint.h>

#define B_    8
#define N_    3136
#define DIM_  147
#define KP_   160
#define TOK_  (B_*N_)      // 25088
#define QKV3_ 192
#define NSPLIT 4

typedef __attribute__((ext_vector_type(4)))  float f32x4;
typedef __attribute__((ext_vector_type(16))) float f32x16;
typedef __attribute__((ext_vector_type(4)))  unsigned int u32x4;
typedef __attribute__((ext_vector_type(2)))  unsigned int u32x2;
typedef __attribute__((ext_vector_type(8)))  short short8;
typedef float f32x4u __attribute__((ext_vector_type(4), aligned(4)));  // 4B-aligned vector load
typedef union { short8 s; u32x4 u; } pk8;

static __device__ __forceinline__ unsigned short f2b(float f){
  unsigned int u = __float_as_uint(f);
  u += 0x7fffu + ((u>>16)&1u);          // RNE
  return (unsigned short)(u>>16);
}
static __device__ __forceinline__ unsigned int pk2(float a, float b){   // RNE pack
  return ((unsigned int)f2b(b)<<16) | (unsigned int)f2b(a);
}
static __device__ __forceinline__ unsigned int pk2t(float a, float b){  // trunc pack (P only)
  return (__float_as_uint(b) & 0xffff0000u) | (__float_as_uint(a)>>16);
}
static __device__ __forceinline__ float b2f(unsigned short s){
  return __uint_as_float(((unsigned int)s)<<16);
}

// async global->LDS, 16 B per lane; LDS dest = uniform base + lane*16
#define GLD16(gp, lp) __builtin_amdgcn_global_load_lds( \
    reinterpret_cast<const uint32_t __attribute__((address_space(1)))*>(reinterpret_cast<uintptr_t>(gp)), \
    reinterpret_cast<uint32_t __attribute__((address_space(3)))*>(reinterpret_cast<uintptr_t>(lp)), \
    16, 0, 0)

// ---------------------------------------------------------------- K1: fused LN1 + QKV GEMM
__global__ __launch_bounds__(256) void k_qkv(const float* __restrict__ x,
                                             const float* __restrict__ w1,
                                             const float* __restrict__ b1,
                                             const float* __restrict__ qkvw,
                                             const float* __restrict__ scale,
                                             unsigned short* __restrict__ qb,
                                             unsigned short* __restrict__ kb,
                                             unsigned short* __restrict__ vtb,
                                             unsigned short* __restrict__ vfb){
  __shared__ alignas(16) unsigned short Wb[192*168];  // 64512 B; aliased by A_ and VT
  unsigned short* A_ = Wb;
  unsigned short* VT = Wb;
  int tid = threadIdx.x;
  int w = tid>>6, lane = tid&63, quad = lane>>4, l16 = lane&15;
  int t0 = blockIdx.x*64;
  float sc2 = scale[0] * 1.44269504089f;

  #pragma unroll
  for(int half=0; half<2; half++){
    int g = half*32 + (tid>>3), e = tid&7;
    const float* xr = x + (size_t)(t0+g)*147;
    f32x4u xv[5];
    float s = 0.f, sq = 0.f;
    #pragma unroll
    for(int j=0;j<5;j++){
      int k = e + 8*j;                      // chunk index, cols 4k..4k+3
      int keff = (k > 36) ? 36 : k;         // clamp addr (masked lanes reuse chunk 36)
      f32x4u v = *(const f32x4u*)(xr + 4*keff);
      if(j == 4){                           // k in [32,39]: mask tail
        v[0] = (k<=36) ? v[0] : 0.f;
        v[1] = (k<=36) ? v[1] : 0.f;
        v[2] = (k<=36) ? v[2] : 0.f;
        v[3] = (k< 36) ? v[3] : 0.f;        // col 147 invalid at k==36
      }
      xv[j] = v;
      s  += (v[0]+v[1]) + (v[2]+v[3]);
      sq += (v[0]*v[0]+v[1]*v[1]) + (v[2]*v[2]+v[3]*v[3]);
    }
    s  += __shfl_xor(s,1,64);  s  += __shfl_xor(s,2,64);  s  += __shfl_xor(s,4,64);
    sq += __shfl_xor(sq,1,64); sq += __shfl_xor(sq,2,64); sq += __shfl_xor(sq,4,64);
    float mean = s*(1.f/147.f);
    float var  = sq*(1.f/147.f) - mean*mean;
    float rstd = rsqrtf(var + 1e-5f);
    #pragma unroll
    for(int j=0;j<5;j++){
      int k = e + 8*j;
      unsigned int lo = 0u, hi = 0u;
      if(k <= 36){
        int c0 = 4*k;
        int c3 = (k==36) ? 146 : c0+3;      // don't read w1/b1 past 146
        float y0 = (xv[j][0]-mean)*rstd*w1[c0]   + b1[c0];
        float y1 = (xv[j][1]-mean)*rstd*w1[c0+1] + b1[c0+1];
        float y2 = (xv[j][2]-mean)*rstd*w1[c0+2] + b1[c0+2];
        float y3 = (xv[j][3]-mean)*rstd*w1[c3]   + b1[c3];
        if(k == 36) y3 = 0.f;               // col 147 -> 0 (K padding)
        lo = pk2(y0,y1); hi = pk2(y2,y3);
      }
      *(u32x2*)(A_ + g*168 + 4*k) = (u32x2){lo,hi};   // k>36 lanes zero cols 148..159
    }
  }
  __syncthreads();
  short8 Af[5];
  #pragma unroll
  for(int kk=0;kk<5;kk++)
    Af[kk] = *(const short8*)(A_ + (w*16+l16)*168 + kk*32 + quad*8);
  __syncthreads();
  {
    // stage qkv weights: convert f32 -> bf16 inline
    unsigned int* dst = (unsigned int*)Wb;
    #pragma unroll
    for(int rep=0; rep<15; rep++){
      int idx = rep*256 + tid;
      int row = idx/20, c = idx - row*20;
      u32x4 o = (u32x4){0u,0u,0u,0u};
      if(c < 19){
        const float* sp = qkvw + row*147 + c*8;
        f32x4u a = *(const f32x4u*)sp;
        o[0] = pk2(a[0],a[1]);
        if(c < 18){
          f32x4u bv = *(const f32x4u*)(sp+4);
          o[1] = pk2(a[2],a[3]);
          o[2] = pk2(bv[0],bv[1]);
          o[3] = pk2(bv[2],bv[3]);
        } else {
          o[1] = pk2(a[2],0.f);             // col 147 of row = next row's elem -> masked
        }
      }
      *(u32x4*)(dst + row*84 + c*4) = o;
    }
  }
  __syncthreads();
  f32x4 acc[12];
  #pragma unroll
  for(int i=0;i<12;i++) acc[i] = (f32x4){0.f,0.f,0.f,0.f};
  #pragma unroll
  for(int nt=0;nt<12;nt++){
    #pragma unroll
    for(int kk=0;kk<5;kk++){
      short8 Bf = *(const short8*)(Wb + (nt*16+l16)*168 + kk*32 + quad*8);
      acc[nt] = __builtin_amdgcn_mfma_f32_16x16x32_bf16(Af[kk], Bf, acc[nt], 0,0,0);
    }
  }
  #pragma unroll
  for(int nt=0;nt<12;nt++){
    int o = nt*16 + l16;
    #pragma unroll
    for(int r=0;r<4;r++){
      int tl = w*16 + quad*4 + r;
      int mg = t0 + tl;
      float val = acc[nt][r];
      if(o < 64)        qb[(size_t)mg*64 + o]        = f2b(val*sc2);
      else if(o < 128)  kb[(size_t)mg*64 + (o-64)]   = f2b(val);
      else              vfb[(size_t)mg*64 + (o-128)] = f2b(val);
    }
  }
  __syncthreads();
  #pragma unroll
  for(int nt=8;nt<12;nt++){
    int hd = (nt-8)*16 + l16;
    #pragma unroll
    for(int r=0;r<4;r++)
      VT[hd*72 + (w*16 + quad*4 + r)] = f2b(acc[nt][r]);
  }
  __syncthreads();
  {
    int b = t0 / N_, n0 = t0 - b*N_;
    const unsigned int* VT32 = (const unsigned int*)VT;
    unsigned int* vg = (unsigned int*)vtb + ((size_t)b*64)*(N_/2) + (n0>>1);
    #pragma unroll
    for(int rep=0;rep<8;rep++){
      int f = rep*256 + tid;
      int row = f>>5, c = f&31;
      vg[(size_t)row*(N_/2) + c] = VT32[row*36 + c];
    }
  }
}

// ---------------------------------------------------------------- K2: attention — R16: 4-wave/128q + QUAD-buffer depth-3 pipeline
// Ledger: R2 dbuf+barriers=43us; R1 depth-1 prefetch=flat; R4 4-wave=flat; R5 reg-gather=60;
// R6 barrier-free=56. => barriers/TLP aren't the cost; depth-1 prefetch too shallow: per-tile
// compute ~500cyc < load+LDS-write completion ~1500cyc under full-chip L2 load. Fix: 4 LDS
// buffers (4x16KB), prefetch 3 tiles ahead, steady-state s_waitcnt vmcnt(8) (2 tiles in
// flight, never 0 mid-loop), ONE barrier/tile (WAR distance now 3 tiles -> data-ready
// barrier subsumes it). Staging split 4 ways (4 GLD16/wave/tile). LDS 64KB -> 2 blocks/CU
// x 4 waves = 8 waves/CU.
__global__ __launch_bounds__(256,2) void k_attn(const unsigned short* __restrict__ qb,
                                                const unsigned short* __restrict__ kb,
                                                const unsigned short* __restrict__ vtb,
                                                unsigned short* __restrict__ Opart,
                                                float* __restrict__ lpart){
  __shared__ alignas(16) char LB[65536];   // 4 x [K 8KB | V 8KB]; first 32KB reused for merge
  __shared__ float Lr[256];
  int tid = threadIdx.x;
  int s = tid>>6;                // wave id 0..3
  int w2 = s>>1;                 // q-pair index
  int w  = s&1;                  // kv-half for compute
  int lane = tid&63;
  int h = lane>>5, l32 = lane&31, l7 = l32&7;
  int qt = blockIdx.x, sp = blockIdx.y, b = blockIdx.z;
  int qtile = 2*qt + w2;         // 64-row q tile, 0..48 valid
  int live = (qtile < 49);
  int q0 = live ? qtile*64 : 0;  // clamp dead pair's reads to a valid tile
  int kv0 = (sp*49)>>2, kv1 = ((sp+1)*49)>>2;
  int nt = kv1 - kv0;            // 12 or 13 (>=3 always)

  // Q B-frags (32x32x16): n=l32 -> q=q0+32qh+l32; k=8h+i -> hd=16kc+8h+i
  short8 Qf[2][4];
  {
    const unsigned short* qg = qb + ((size_t)b*N_ + q0)*64;
    #pragma unroll
    for(int qh=0;qh<2;qh++)
      #pragma unroll
      for(int kc=0;kc<4;kc++)
        Qf[qh][kc] = *(const short8*)(qg + (32*qh + l32)*64 + 16*kc + 8*h);
  }
  // staging role: waves 0,1 stage K halves; waves 2,3 stage V halves (wh = half index)
  int isK = (s < 2);
  int wh  = s & 1;
  int offG[4];
  {
    int pl = lane>>3, cl = lane&7;
    #pragma unroll
    for(int rr=0;rr<4;rr++){
      int p = rr*8 + pl;
      int cx = cl ^ (p&7);                               // XOR col swizzle
      if(isK){
        int sig = (p & 0x13) | ((p&4)<<1) | ((p&8)>>1);  // swap bits 2<->3
        offG[rr] = (32*wh + sig)*128 + cx*16;            // K: sigma'd row, byte col
      } else {
        offG[rr] = (32*wh + p)*(N_*2) + cx*16;           // V^T: plain hd row
      }
    }
  }
  const char* sBase = isK ? ((const char*)kb  + (size_t)b*N_*128)
                          : ((const char*)vtb + (size_t)b*64*(size_t)(N_*2));
  int tileStride = isK ? 8192 : 128;
  int ldsOff = (isK ? 0 : 8192) + wh*4096;               // within a 16KB tile buffer

#define STAGE(BUFI, T) { \
    const char* tp_ = sBase + (size_t)(T)*tileStride; \
    char* db_ = LB + (BUFI)*16384 + ldsOff; \
    _Pragma("unroll") \
    for(int rr=0;rr<4;rr++) GLD16(tp_ + offG[rr], db_ + rr*1024); }

  f32x16 O[2][2];
  #pragma unroll
  for(int qh=0;qh<2;qh++) for(int hdq=0;hdq<2;hdq++)
    #pragma unroll
    for(int r=0;r<16;r++) O[qh][hdq][r] = 0.f;
  float lracc[2][4];
  #pragma unroll
  for(int qh=0;qh<2;qh++)
    #pragma unroll
    for(int j=0;j<4;j++) lracc[qh][j] = 0.f;

  // prologue: tiles 0,1,2 -> buffers 0,1,2 (12 loads in flight per wave)
  STAGE(0, kv0);
  STAGE(1, kv0+1);
  STAGE(2, kv0+2);

  for(int i=0;i<nt;i++){
    int kvt = kv0 + i;
    // wait for THIS tile's 4 loads only; up to 8 newer stay in flight (T4: counted, never 0 mid-loop)
    if(i <= nt-3)      { asm volatile("s_waitcnt vmcnt(8)" ::: "memory"); }
    else if(i == nt-2) { asm volatile("s_waitcnt vmcnt(4)" ::: "memory"); }
    else               { asm volatile("s_waitcnt vmcnt(0)" ::: "memory"); }
    __builtin_amdgcn_s_barrier();          // all 4 waves' quarters of tile i visible;
                                           // also: all waves finished compute(i-1) -> WAR for buf (i+3)&3
    __builtin_amdgcn_sched_barrier(0);     // pin: no ds_read hoisted above barrier
    if(i+3 < nt) STAGE((i+3)&3, kvt+3);    // refill pipeline (back to 12 in flight)

    if(live){
      const char* cb = LB + (i&3)*16384;
      const unsigned short* Kh = (const unsigned short*)cb + w*2048;
      const unsigned short* Vh = (const unsigned short*)cb + 4096;

      short8 Kf[4];
      #pragma unroll
      for(int kc=0;kc<4;kc++)
        Kf[kc] = *(const short8*)(Kh + l32*64 + (((2*kc+h) ^ l7)&7)*8);
      #pragma unroll
      for(int qh=0;qh<2;qh++){
        f32x16 S;
        #pragma unroll
        for(int r=0;r<16;r++) S[r] = 0.f;
        #pragma unroll
        for(int kc=0;kc<4;kc++)
          S = __builtin_amdgcn_mfma_f32_32x32x16_bf16(Kf[kc], Qf[qh][kc], S, 0,0,0);
        f32x16 E;
        if(kvt == qtile){                // diagonal tile (wave-uniform branch)
          int dref = 32*qh + l32 - 32*w - 8*h;
          #pragma unroll
          for(int r=0;r<16;r++){
            int kvl = 16*((r>>3)&1) + 4*((r>>2)&1) + (r&3);
            float pv = (kvl == dref) ? 0.f : __builtin_amdgcn_exp2f(S[r]);
            E[r] = pv; lracc[qh][r&3] += pv;
          }
        } else {
          #pragma unroll
          for(int r=0;r<16;r++){
            float pv = __builtin_amdgcn_exp2f(S[r]);
            E[r] = pv; lracc[qh][r&3] += pv;
          }
        }
        pk8 Pb0, Pb1;
        Pb0.u = (u32x4){ pk2t(E[0],E[1]),   pk2t(E[2],E[3]),
                         pk2t(E[4],E[5]),   pk2t(E[6],E[7]) };
        Pb1.u = (u32x4){ pk2t(E[8],E[9]),   pk2t(E[10],E[11]),
                         pk2t(E[12],E[13]), pk2t(E[14],E[15]) };
        #pragma unroll
        for(int hdq=0;hdq<2;hdq++){
          short8 Vf0 = *(const short8*)(Vh + (32*hdq + l32)*64 + (((4*w + h) ^ l7)&7)*8);
          short8 Vf1 = *(const short8*)(Vh + (32*hdq + l32)*64 + (((4*w + 2 + h) ^ l7)&7)*8);
          O[qh][hdq] = __builtin_amdgcn_mfma_f32_32x32x16_bf16(Vf0, Pb0.s, O[qh][hdq], 0,0,0);
          O[qh][hdq] = __builtin_amdgcn_mfma_f32_32x32x16_bf16(Vf1, Pb1.s, O[qh][hdq], 0,0,0);
        }
      }
    }
    __builtin_amdgcn_sched_barrier(0);     // pin: keep this tile's ds_reads before next iteration
  }
#undef STAGE

  float lr[2];
  #pragma unroll
  for(int qh=0;qh<2;qh++)
    lr[qh] = (lracc[qh][0] + lracc[qh][1]) + (lracc[qh][2] + lracc[qh][3]);
  lr[0] += __shfl_xor(lr[0],32,64);
  lr[1] += __shfl_xor(lr[1],32,64);
  __syncthreads();                     // all tile reads done -> LB free for merge
  unsigned int* Lp = (unsigned int*)LB + w2*4096;      // per-pair 16KB merge region
  float* Lrp = Lr + w2*128;
  if(w == 0){
    #pragma unroll
    for(int qh=0;qh<2;qh++)
      #pragma unroll
      for(int hdq=0;hdq<2;hdq++)
        #pragma unroll
        for(int r=0;r<16;r++)
          Lp[(qh*32 + hdq*16 + r)*64 + lane] = __float_as_uint(O[qh][hdq][r]);
    Lrp[lane]      = lr[0];
    Lrp[64 + lane] = lr[1];
  }
  __syncthreads();
  if(w == 1){
    #pragma unroll
    for(int qh=0;qh<2;qh++)
      #pragma unroll
      for(int hdq=0;hdq<2;hdq++)
        #pragma unroll
        for(int r=0;r<16;r++)
          O[qh][hdq][r] += __uint_as_float(Lp[(qh*32 + hdq*16 + r)*64 + lane]);
    float lt0 = lr[0] + Lrp[lane];
    float lt1 = lr[1] + Lrp[64 + lane];
    size_t lb = (size_t)sp*TOK_ + (size_t)b*N_ + q0;
    if(live && lane < 32){ lpart[lb + lane] = lt0; lpart[lb + 32 + lane] = lt1; }
    // transpose O^T -> [q][hd] bf16 in Lp (in-wave DS ordering: reads above precede writes)
    #pragma unroll
    for(int qh=0;qh<2;qh++){
      int q = 32*qh + l32;
      #pragma unroll
      for(int hdq=0;hdq<2;hdq++)
        #pragma unroll
        for(int k2=0;k2<8;k2++){
          int idx = 16*hdq + 4*(k2>>1) + 2*h + (k2&1);
          Lp[q*36 + idx] = pk2(O[qh][hdq][2*k2], O[qh][hdq][2*k2+1]);
        }
    }
    if(live){
      unsigned int* og = (unsigned int*)(Opart + ((size_t)sp*TOK_ + (size_t)b*N_ + q0)*64);
      #pragma unroll
      for(int rep=0;rep<8;rep++){
        int f = rep*64 + lane;
        int row = f>>3, c4 = f&7;
        *(u32x4*)(og + row*32 + c4*4) = *(const u32x4*)&Lp[row*36 + c4*4];
      }
    }
  }
}

// ---------------------------------------------------------------- K3: merge + proj + residual(v) + LN2 + MLP + residual
__global__ __launch_bounds__(256) void k_mlp(const unsigned short* __restrict__ Opart,
                                             const float* __restrict__ lpart,
                                             const unsigned short* __restrict__ vfb,
                                             const float* __restrict__ projw,
                                             const float* __restrict__ fc1w,
                                             const float* __restrict__ fc2w,
                                             const float* __restrict__ projb,
                                             const float* __restrict__ n2w,
                                             const float* __restrict__ n2b,
                                             const float* __restrict__ fc1b,
                                             const float* __restrict__ fc2b,
                                             float* __restrict__ out){
  __shared__ alignas(16) unsigned short Ws[3][64*72];
  __shared__ alignas(16) unsigned short Xs[64*72];
  unsigned int* Xs32 = (unsigned int*)Xs;
  int tid = threadIdx.x;
  int w = tid>>6, lane = tid&63, quad = lane>>4, l16 = lane&15;
  int t0 = blockIdx.x*64;

  {
    #pragma unroll
    for(int rep=0;rep<2;rep++){
      int f = rep*256 + tid;
      int row = f>>3, c = f&7;
      int so = (row<<6) + (c<<3);          // f32 src offset, 16B-aligned
      f32x4 a0 = *(const f32x4*)(projw + so), b0 = *(const f32x4*)(projw + so + 4);
      f32x4 a1 = *(const f32x4*)(fc1w  + so), b1v = *(const f32x4*)(fc1w  + so + 4);
      f32x4 a2 = *(const f32x4*)(fc2w  + so), b2 = *(const f32x4*)(fc2w  + so + 4);
      *(u32x4*)((unsigned int*)Ws[0] + row*36 + c*4) =
        (u32x4){pk2(a0[0],a0[1]),pk2(a0[2],a0[3]),pk2(b0[0],b0[1]),pk2(b0[2],b0[3])};
      *(u32x4*)((unsigned int*)Ws[1] + row*36 + c*4) =
        (u32x4){pk2(a1[0],a1[1]),pk2(a1[2],a1[3]),pk2(b1v[0],b1v[1]),pk2(b1v[2],b1v[3])};
      *(u32x4*)((unsigned int*)Ws[2] + row*36 + c*4) =
        (u32x4){pk2(a2[0],a2[1]),pk2(a2[2],a2[3]),pk2(b2[0],b2[1]),pk2(b2[2],b2[3])};
    }
  }
  #pragma unroll
  for(int i=0;i<2;i++){
    int f = i*256 + tid;
    int row = f>>3, c = f&7;
    float lo[4] = {0,0,0,0}, hi[4] = {0,0,0,0};
    float lsum = 0.f;
    #pragma unroll
    for(int s=0;s<NSPLIT;s++){
      u32x4 a = *((const u32x4*)(Opart + ((size_t)s*TOK_ + t0)*64) + row*8 + c);
      #pragma unroll
      for(int k=0;k<4;k++){
        lo[k] += __uint_as_float(a[k]<<16);
        hi[k] += __uint_as_float(a[k] & 0xffff0000u);
      }
      lsum += lpart[(size_t)s*TOK_ + t0 + row];
    }
    float linv = 1.f/lsum;
    u32x4 o;
    #pragma unroll
    for(int k=0;k<4;k++) o[k] = pk2(lo[k]*linv, hi[k]*linv);
    *(u32x4*)&Xs32[row*36 + c*4] = o;
  }
  __syncthreads();

  short8 Af[2];
  #pragma unroll
  for(int kk=0;kk<2;kk++)
    Af[kk] = *(const short8*)(Xs + (w*16+l16)*72 + kk*32 + quad*8);
  f32x4 acc[4];
  #pragma unroll
  for(int i=0;i<4;i++) acc[i] = (f32x4){0.f,0.f,0.f,0.f};
  #pragma unroll
  for(int jt=0;jt<4;jt++)
    #pragma unroll
    for(int kk=0;kk<2;kk++){
      short8 Bf = *(const short8*)(Ws[0] + (jt*16+l16)*72 + kk*32 + quad*8);
      acc[jt] = __builtin_amdgcn_mfma_f32_16x16x32_bf16(Af[kk], Bf, acc[jt], 0,0,0);
    }
  float xa[4][4];
  #pragma unroll
  for(int jt=0;jt<4;jt++){
    int col = jt*16 + l16;
    float pb = projb[col];
    #pragma unroll
    for(int r=0;r<4;r++){
      int tg = t0 + w*16 + quad*4 + r;
      xa[jt][r] = acc[jt][r] + pb + b2f(vfb[(size_t)tg*64 + col]);
    }
  }
  #pragma unroll
  for(int r=0;r<4;r++){
    float s = 0.f, sq = 0.f;
    #pragma unroll
    for(int jt=0;jt<4;jt++){ s += xa[jt][r]; sq += xa[jt][r]*xa[jt][r]; }
    s  += __shfl_xor(s,1,64);  s  += __shfl_xor(s,2,64);
    s  += __shfl_xor(s,4,64);  s  += __shfl_xor(s,8,64);
    sq += __shfl_xor(sq,1,64); sq += __shfl_xor(sq,2,64);
    sq += __shfl_xor(sq,4,64); sq += __shfl_xor(sq,8,64);
    float mu = s*(1.f/64.f);
    float var = sq*(1.f/64.f) - mu*mu;
    float rstd = rsqrtf(var + 1e-5f);
    #pragma unroll
    for(int jt=0;jt<4;jt++){
      int col = jt*16 + l16;
      Xs[(w*16+quad*4+r)*72 + col] = f2b((xa[jt][r]-mu)*rstd*n2w[col] + n2b[col]);
    }
  }
  #pragma unroll
  for(int kk=0;kk<2;kk++)
    Af[kk] = *(const short8*)(Xs + (w*16+l16)*72 + kk*32 + quad*8);
  f32x4 acc2[4];
  #pragma unroll
  for(int i=0;i<4;i++) acc2[i] = (f32x4){0.f,0.f,0.f,0.f};
  #pragma unroll
  for(int jt=0;jt<4;jt++)
    #pragma unroll
    for(int kk=0;kk<2;kk++){
      short8 Bf = *(const short8*)(Ws[1] + (jt*16+l16)*72 + kk*32 + quad*8);
      acc2[jt] = __builtin_amdgcn_mfma_f32_16x16x32_bf16(Af[kk], Bf, acc2[jt], 0,0,0);
    }
  #pragma unroll
  for(int jt=0;jt<4;jt++){
    int col = jt*16 + l16;
    float fb = fc1b[col];
    #pragma unroll
    for(int r=0;r<4;r++){
      float g = acc2[jt][r] + fb;
      float z = g*0.70710678118f;
      float az = fabsf(z);
      float t = 1.f/(1.f + 0.3275911f*az);
      float poly = ((((1.061405429f*t - 1.453152027f)*t + 1.421413741f)*t - 0.284496736f)*t + 0.254829592f)*t;
      float er = 1.f - poly*__builtin_amdgcn_exp2f(-az*az*1.44269504089f);
      er = (z < 0.f) ? -er : er;
      Xs[(w*16+quad*4+r)*72 + col] = f2b(0.5f*g*(1.f + er));
    }
  }
  #pragma unroll
  for(int kk=0;kk<2;kk++)
    Af[kk] = *(const short8*)(Xs + (w*16+l16)*72 + kk*32 + quad*8);
  f32x4 acc3[4];
  #pragma unroll
  for(int i=0;i<4;i++) acc3[i] = (f32x4){0.f,0.f,0.f,0.f};
  #pragma unroll
  for(int jt=0;jt<4;jt++)
    #pragma unroll
    for(int kk=0;kk<2;kk++){
      short8 Bf = *(const short8*)(Ws[2] + (jt*16+l16)*72 + kk*32 + quad*8);
      acc3[jt] = __builtin_amdgcn_mfma_f32_16x16x32_bf16(Af[kk], Bf, acc3[jt], 0,0,0);
    }
  #pragma unroll
  for(int jt=0;jt<4;jt++){
    int col = jt*16 + l16;
    float ob2 = fc2b[col];
    #pragma unroll
    for(int r=0;r<4;r++){
      int tg = t0 + w*16 + quad*4 + r;
      out[(size_t)tg*64 + col] = xa[jt][r] + acc3[jt][r] + ob2;
    }
  }
}

// ---------------------------------------------------------------- launch
extern "C" void kernel_launch(void* const* d_in, const int* in_sizes, int n_in,
                              void* d_out, int out_size, void* d_ws, size_t ws_size,
                              hipStream_t stream){
  const float* x     = (const float*)d_in[0];
  const float* n1w   = (const float*)d_in[1];
  const float* n1b   = (const float*)d_in[2];
  const float* qkvw  = (const float*)d_in[3];
  const float* scale = (const float*)d_in[4];
  const float* projw = (const float*)d_in[5];
  const float* projb = (const float*)d_in[6];
  const float* n2w   = (const float*)d_in[7];
  const float* n2b   = (const float*)d_in[8];
  const float* fc1w  = (const float*)d_in[9];
  const float* fc1b  = (const float*)d_in[10];
  const float* fc2w  = (const float*)d_in[11];
  const float* fc2b  = (const float*)d_in[12];

  char* base = (char*)d_ws;
  unsigned short* qb  = (unsigned short*)(base + 0);          //  3211264
  unsigned short* kb  = (unsigned short*)(base + 3211264);    //  3211264
  unsigned short* vtb = (unsigned short*)(base + 6422528);    //  3211264
  unsigned short* vfb = (unsigned short*)(base + 9633792);    //  3211264
  unsigned short* Op  = (unsigned short*)(base + 12845056);   // 12845056 (4 splits bf16)
  float*          lp  = (float*)(base + 25690112);            //   401408  -> total 26091520

  hipLaunchKernelGGL(k_qkv,  dim3(TOK_/64),    dim3(256), 0, stream,
                     x, n1w, n1b, qkvw, scale, qb, kb, vtb, vfb);
  hipLaunchKernelGGL(k_attn, dim3(25,NSPLIT,8), dim3(256), 0, stream, qb, kb, vtb, Op, lp);
  hipLaunchKernelGGL(k_mlp,  dim3(TOK_/64),    dim3(256), 0, stream, Op, lp, vfb,
                     projw, fc1w, fc2w, projb, n2w, n2b, fc1b, fc2b, (float*)d_out);
}